// Round 6
// baseline (182.451 us; speedup 1.0000x reference)
//
#include <hip/hip_runtime.h>
#include <hip/hip_bf16.h>
#include <math.h>

#define N_CLASSES 1000
#define FEAT_DIM 1024
#define PROJ_DIM 256
#define BATCH 32
#define NUM_SUPPORT 8192
#define KBIG 3072   // [Ah | Ah | Al] x [Wh ; Wl ; Wh]
#define ACOLS 2048  // stored A: row = [Ah(1024) | Al(1024)]
#define KSLICES 4
#define KSLICE (KBIG / KSLICES)  // 768 = 12 chunks of 64

// prelude grid layout
#define PA_BLOCKS 8192  // prep_a
#define PW_BLOCKS 1024  // prep_w
#define PX_BLOCKS 256   // proj_x (32 b x 8 cc)

typedef __attribute__((ext_vector_type(8))) short bf16x8;
typedef __attribute__((ext_vector_type(4))) float f32x4;

__device__ inline unsigned short bf16bits(float v) {
  __hip_bfloat16 h = __float2bfloat16(v);
  return *reinterpret_cast<unsigned short*>(&h);
}
__device__ inline float bf16tof(unsigned short u) {
  __hip_bfloat16 h;
  *reinterpret_cast<unsigned short*>(&h) = u;
  return __bfloat162float(h);
}

// Monotonic float <-> unsigned encoding for atomicMax on floats.
__device__ inline unsigned enc_f(float f) {
  unsigned u = __float_as_uint(f);
  return (u & 0x80000000u) ? ~u : (u | 0x80000000u);
}
__device__ inline float dec_f(unsigned e) {
  return (e & 0x80000000u) ? __uint_as_float(e & 0x7FFFFFFFu)
                           : __uint_as_float(~e);
}

// ---------------------------------------------------------------------------
// Prelude (one dispatch): prep_a | prep_w | proj_x + rowmax init.
// Branch is uniform per block (on blockIdx), so __syncthreads stays legal.
// ---------------------------------------------------------------------------
__global__ __launch_bounds__(256) void prelude_kernel(
    const float* __restrict__ sx, const float* __restrict__ W,
    const float* __restrict__ x, unsigned short* __restrict__ A2,
    unsigned short* __restrict__ WT, float* __restrict__ xq,
    unsigned* __restrict__ rowmaxU) {
  __shared__ float part[256];
  const int bid = blockIdx.x;
  const int t = threadIdx.x;

  if (bid < PA_BLOCKS) {
    // ---- prep_a: sx row -> [hi(1024) | lo(1024)] bf16
    const int idx = bid * 256 + t;
    const int r = idx >> 8;
    const int q = idx & 255;
    const float4 v = *(const float4*)&sx[(size_t)r * FEAT_DIM + q * 4];
    const float vv[4] = {v.x, v.y, v.z, v.w};
    ushort4 h, l;
    unsigned short hb[4], lb[4];
#pragma unroll
    for (int i = 0; i < 4; i++) {
      hb[i] = bf16bits(vv[i]);
      lb[i] = bf16bits(vv[i] - bf16tof(hb[i]));
    }
    h.x = hb[0]; h.y = hb[1]; h.z = hb[2]; h.w = hb[3];
    l.x = lb[0]; l.y = lb[1]; l.z = lb[2]; l.w = lb[3];
    *(ushort4*)&A2[(size_t)r * ACOLS + q * 4] = h;
    *(ushort4*)&A2[(size_t)r * ACOLS + 1024 + q * 4] = l;
  } else if (bid < PA_BLOCKS + PW_BLOCKS) {
    // ---- prep_w: WT[n] = [Wh | Wl | Wh]
    const int idx = (bid - PA_BLOCKS) * 256 + t;
    const int n = idx >> 10;
    const int k = idx & 1023;
    const float v = W[(size_t)k * PROJ_DIM + n];
    const unsigned short h = bf16bits(v);
    const unsigned short l = bf16bits(v - bf16tof(h));
    WT[(size_t)n * KBIG + k] = h;
    WT[(size_t)n * KBIG + 1024 + k] = l;
    WT[(size_t)n * KBIG + 2048 + k] = h;
  } else {
    // ---- proj_x: xq = x @ W (fp32), 32 cols x 8 k-slices per block
    const int pxb = bid - PA_BLOCKS - PW_BLOCKS;
    const int b = pxb >> 3, cc = pxb & 7;
    if (pxb == 0 && t < BATCH) rowmaxU[t] = 0u;  // encoded -inf

    const int col = t & 31, ks = t >> 5;
    const int gc = cc * 32 + col;
    const int k0 = ks * 128;
    float s = 0.f;
#pragma unroll 8
    for (int k = 0; k < 128; k++) {
      s = fmaf(x[(size_t)b * FEAT_DIM + k0 + k],
               W[(size_t)(k0 + k) * PROJ_DIM + gc], s);
    }
    part[t] = s;
    __syncthreads();
    if (t < 32) {
      float acc = 0.f;
#pragma unroll
      for (int i = 0; i < 8; i++) acc += part[i * 32 + t];
      xq[(size_t)b * PROJ_DIM + cc * 32 + t] = acc;
    }
  }
}

// ---------------------------------------------------------------------------
// sxpP[kz] = A2(slice kz) @ WT^T via MFMA. K=3072 in 4 slices of 768.
// Tile 128x64, BK=64, 4 waves (2x2), wave tile 64x32 (4x2 frags of 16x16x32).
// Grid (64, 4, 4) = 1024 blocks (4 resident/CU). Plain stores into per-slice
// partial buffers — NO atomics (round-5 lesson: cross-XCD atomic combine
// serializes; 8-way atomic split-K was 60 µs vs 43 for none).
// ---------------------------------------------------------------------------
__global__ __launch_bounds__(256) void sxp_mfma_kernel(
    const unsigned short* __restrict__ A2, const unsigned short* __restrict__ WT,
    float* __restrict__ sxpP) {
  __shared__ unsigned short At[128 * 64];  // row r: 8 chunks of 8 shorts
  __shared__ unsigned short Bt[64 * 64];

  const int tid = threadIdx.x;
  const int w = tid >> 6;
  const int lane = tid & 63;
  const int bm = blockIdx.x * 128;
  const int bn = blockIdx.y * 64;
  const int kz = blockIdx.z;
  const int wm = w & 1, wn = w >> 1;
  const int m16 = lane & 15, quad = lane >> 4;
  const int lrow8 = lane >> 3;       // 0..7
  const int g = (lane & 7) ^ lrow8;  // XOR-swizzled global chunk index

  f32x4 acc[4][2];
#pragma unroll
  for (int mt = 0; mt < 4; mt++)
#pragma unroll
    for (int nt = 0; nt < 2; nt++) acc[mt][nt] = (f32x4){0.f, 0.f, 0.f, 0.f};

  const int kb0 = kz * KSLICE;
  for (int kk = 0; kk < KSLICE; kk += 64) {
    const int kb = kb0 + kk;
    const int acol = (kb < 1024) ? kb : kb - 1024;
    // stage A tile (128 x 64 bf16): 4 instrs/wave, 8 rows each
#pragma unroll
    for (int i = 0; i < 4; i++) {
      const int row = w * 32 + i * 8 + lrow8;
      const unsigned short* gp = A2 + (size_t)(bm + row) * ACOLS + acol + g * 8;
      __builtin_amdgcn_global_load_lds(
          (const __attribute__((address_space(1))) void*)gp,
          (__attribute__((address_space(3))) void*)(At + (w * 32 + i * 8) * 64),
          16, 0, 0);
    }
    // stage B tile (64 n x 64 k bf16): 2 instrs/wave
#pragma unroll
    for (int i = 0; i < 2; i++) {
      const int nrow = w * 16 + i * 8 + lrow8;
      const unsigned short* gp = WT + (size_t)(bn + nrow) * KBIG + kb + g * 8;
      __builtin_amdgcn_global_load_lds(
          (const __attribute__((address_space(1))) void*)gp,
          (__attribute__((address_space(3))) void*)(Bt + (w * 16 + i * 8) * 64),
          16, 0, 0);
    }
    __syncthreads();

#pragma unroll
    for (int s = 0; s < 2; s++) {
      const int slot = (s * 4 + quad) ^ (m16 & 7);
      bf16x8 af[4], bf[2];
#pragma unroll
      for (int mt = 0; mt < 4; mt++) {
        const int row = wm * 64 + mt * 16 + m16;
        af[mt] = *(bf16x8*)&At[row * 64 + slot * 8];
      }
#pragma unroll
      for (int nt = 0; nt < 2; nt++) {
        const int nrow = wn * 32 + nt * 16 + m16;
        bf[nt] = *(bf16x8*)&Bt[nrow * 64 + slot * 8];
      }
#pragma unroll
      for (int mt = 0; mt < 4; mt++)
#pragma unroll
        for (int nt = 0; nt < 2; nt++)
          acc[mt][nt] = __builtin_amdgcn_mfma_f32_16x16x32_bf16(
              af[mt], bf[nt], acc[mt][nt], 0, 0, 0);
    }
    __syncthreads();
  }

  // plain stores into this slice's partial buffer.
  // C/D layout: col = lane&15 (n), row = quad*4 + reg (m)
  float* __restrict__ outP = sxpP + (size_t)kz * NUM_SUPPORT * PROJ_DIM;
#pragma unroll
  for (int mt = 0; mt < 4; mt++)
#pragma unroll
    for (int nt = 0; nt < 2; nt++)
#pragma unroll
      for (int r = 0; r < 4; r++) {
        const int mg = bm + wm * 64 + mt * 16 + quad * 4 + r;
        const int ng = bn + wn * 32 + nt * 16 + m16;
        outP[(size_t)mg * PROJ_DIM + ng] = acc[mt][nt][r];
      }
}

// ---------------------------------------------------------------------------
// score: sum the 4 split-K partials of sxp_j in registers, then
// scores[b][j] = 2<xq_b, sxp_j> - ||sxp_j||^2 - ||xq_b||^2.
// Grid (32 j-chunks, 8 b-groups of 4). x_sq computed in-block.
// ---------------------------------------------------------------------------
__global__ __launch_bounds__(256) void score_kernel(
    const float* __restrict__ xq, const float* __restrict__ sxpP,
    float* __restrict__ sc, unsigned* __restrict__ rowmaxU) {
  __shared__ float xqT4[PROJ_DIM * 4];
  __shared__ float xsqL[4];
  __shared__ float redm[4][4];

  const int t = threadIdx.x;
  const int jc = blockIdx.x;
  const int bg = blockIdx.y;
  const int lane = t & 63, wave = t >> 6;

  float xv[4];
#pragma unroll
  for (int i = 0; i < 4; i++) {
    xv[i] = xq[(size_t)(bg * 4 + i) * PROJ_DIM + t];
    xqT4[t * 4 + i] = xv[i];
  }
#pragma unroll
  for (int i = 0; i < 4; i++) {
    float v = xv[i] * xv[i];
#pragma unroll
    for (int o = 1; o < 64; o <<= 1) v += __shfl_xor(v, o, 64);
    if (lane == 0) redm[i][wave] = v;
  }
  __syncthreads();
  if (t < 4) xsqL[t] = redm[t][0] + redm[t][1] + redm[t][2] + redm[t][3];
  __syncthreads();

  const int j = jc * 256 + t;
  const float4* __restrict__ r0 =
      (const float4*)(sxpP + (size_t)j * PROJ_DIM);
  const float4* __restrict__ r1 =
      (const float4*)(sxpP + (size_t)(NUM_SUPPORT + j) * PROJ_DIM);
  const float4* __restrict__ r2 =
      (const float4*)(sxpP + (size_t)(2 * NUM_SUPPORT + j) * PROJ_DIM);
  const float4* __restrict__ r3 =
      (const float4*)(sxpP + (size_t)(3 * NUM_SUPPORT + j) * PROJ_DIM);
  float dot[4] = {0.f, 0.f, 0.f, 0.f};
  float rsq = 0.f;

#pragma unroll 4
  for (int q = 0; q < PROJ_DIM / 4; q++) {
    const float4 v0 = r0[q], v1 = r1[q], v2 = r2[q], v3 = r3[q];
    float rr[4];
    rr[0] = (v0.x + v1.x) + (v2.x + v3.x);
    rr[1] = (v0.y + v1.y) + (v2.y + v3.y);
    rr[2] = (v0.z + v1.z) + (v2.z + v3.z);
    rr[3] = (v0.w + v1.w) + (v2.w + v3.w);
#pragma unroll
    for (int c = 0; c < 4; c++) {
      const int p = q * 4 + c;
      const float4 xb = *(const float4*)&xqT4[p * 4];
      rsq = fmaf(rr[c], rr[c], rsq);
      dot[0] = fmaf(rr[c], xb.x, dot[0]);
      dot[1] = fmaf(rr[c], xb.y, dot[1]);
      dot[2] = fmaf(rr[c], xb.z, dot[2]);
      dot[3] = fmaf(rr[c], xb.w, dot[3]);
    }
  }

#pragma unroll
  for (int c = 0; c < 4; c++) {
    const float s = 2.0f * dot[c] - rsq - xsqL[c];
    sc[(size_t)(bg * 4 + c) * NUM_SUPPORT + j] = s;
    float v = s;
#pragma unroll
    for (int o = 1; o < 64; o <<= 1) v = fmaxf(v, __shfl_xor(v, o, 64));
    if (lane == 0) redm[c][wave] = v;
  }
  __syncthreads();
  if (t < 4) {
    const float m =
        fmaxf(fmaxf(redm[t][0], redm[t][1]), fmaxf(redm[t][2], redm[t][3]));
    atomicMax(&rowmaxU[bg * 4 + t], enc_f(m));
  }
}

// ---------------------------------------------------------------------------
// finish: exp, class bins, log. One block (1024 thr) per batch row.
// ---------------------------------------------------------------------------
__global__ __launch_bounds__(1024) void finish_kernel(
    const float* __restrict__ sc, const unsigned* __restrict__ rowmaxU,
    const int* __restrict__ sy, float* __restrict__ out) {
  __shared__ float cls[N_CLASSES];
  __shared__ float red[16];

  const int b = blockIdx.x;
  const int t = threadIdx.x;
  const int lane = t & 63, wave = t >> 6;
  const float m = dec_f(rowmaxU[b]);

  for (int c = t; c < N_CLASSES; c += 1024) cls[c] = 0.0f;
  __syncthreads();

  float lsum = 0.0f;
#pragma unroll
  for (int jj = 0; jj < NUM_SUPPORT / 1024; jj++) {
    const int j = jj * 1024 + t;
    const float e = expf(sc[(size_t)b * NUM_SUPPORT + j] - m);
    lsum += e;
    atomicAdd(&cls[sy[j]], e);
  }
#pragma unroll
  for (int o = 1; o < 64; o <<= 1) lsum += __shfl_xor(lsum, o, 64);
  if (lane == 0) red[wave] = lsum;
  __syncthreads();
  if (t == 0) {
    float s = 0.f;
#pragma unroll
    for (int i = 0; i < 16; i++) s += red[i];
    red[0] = s;
  }
  __syncthreads();
  const float inv = 1.0f / red[0];
  for (int c = t; c < N_CLASSES; c += 1024) {
    out[(size_t)b * N_CLASSES + c] = logf(cls[c] * inv + 1e-12f);
  }
}

// ---------------------------------------------------------------------------
extern "C" void kernel_launch(void* const* d_in, const int* in_sizes, int n_in,
                              void* d_out, int out_size, void* d_ws,
                              size_t ws_size, hipStream_t stream) {
  const float* x = (const float*)d_in[0];   // (32, 1024)
  const float* sx = (const float*)d_in[1];  // (8192, 1024)
  const float* W = (const float*)d_in[2];   // (1024, 256)
  const int* sy = (const int*)d_in[3];      // (8192,)
  float* out = (float*)d_out;               // (32, 1000)

  char* p = (char*)d_ws;
  float* xq = (float*)p;            p += (size_t)BATCH * PROJ_DIM * 4;
  unsigned* rowmaxU = (unsigned*)p; p += 128;
  float* sxpP = (float*)p;          p += (size_t)KSLICES * NUM_SUPPORT * PROJ_DIM * 4;
  float* sc = (float*)p;            p += (size_t)BATCH * NUM_SUPPORT * 4;
  unsigned short* A2 = (unsigned short*)p; p += (size_t)NUM_SUPPORT * ACOLS * 2;
  unsigned short* WT = (unsigned short*)p;  // 256*3072*2

  prelude_kernel<<<dim3(PA_BLOCKS + PW_BLOCKS + PX_BLOCKS), dim3(256), 0,
                   stream>>>(sx, W, x, A2, WT, xq, rowmaxU);
  sxp_mfma_kernel<<<dim3(NUM_SUPPORT / 128, PROJ_DIM / 64, KSLICES), dim3(256),
                    0, stream>>>(A2, WT, sxpP);
  score_kernel<<<dim3(NUM_SUPPORT / 256, BATCH / 4), dim3(256), 0, stream>>>(
      xq, sxpP, sc, rowmaxU);
  finish_kernel<<<dim3(BATCH), dim3(1024), 0, stream>>>(sc, rowmaxU, sy, out);
}

// Round 7
// 130.892 us; speedup vs baseline: 1.3939x; 1.3939x over previous
//
#include <hip/hip_runtime.h>
#include <hip/hip_bf16.h>
#include <math.h>

#define N_CLASSES 1000
#define FEAT_DIM 1024
#define PROJ_DIM 256
#define BATCH 32
#define NUM_SUPPORT 8192

// prelude grid layout
#define PA_BLOCKS 8192  // prep_a: one row each
#define PW_BLOCKS 16    // prep_w: 64-k tile each
#define PX_BLOCKS 256   // proj_x (32 b x 8 cc)

typedef __attribute__((ext_vector_type(8))) _Float16 f16x8;
typedef __attribute__((ext_vector_type(4))) _Float16 f16x4;
typedef __attribute__((ext_vector_type(2))) _Float16 f16x2;
typedef __attribute__((ext_vector_type(4))) float f32x4;

// Monotonic float <-> unsigned encoding for atomicMax on floats.
__device__ inline unsigned enc_f(float f) {
  unsigned u = __float_as_uint(f);
  return (u & 0x80000000u) ? ~u : (u | 0x80000000u);
}
__device__ inline float dec_f(unsigned e) {
  return (e & 0x80000000u) ? __uint_as_float(e & 0x7FFFFFFFu)
                           : __uint_as_float(~e);
}

// ---------------------------------------------------------------------------
// Prelude (one dispatch): prep_a (sx->fp16) | prep_w (W -> fp16, n-major) |
// proj_x (fp32) + rowmax init. Branch is uniform per block.
// ---------------------------------------------------------------------------
__global__ __launch_bounds__(256) void prelude_kernel(
    const float* __restrict__ sx, const float* __restrict__ W,
    const float* __restrict__ x, _Float16* __restrict__ A1,
    _Float16* __restrict__ W1, float* __restrict__ xq,
    unsigned* __restrict__ rowmaxU) {
  __shared__ float part[256];
  __shared__ _Float16 Lw[256][66];  // transpose tile, padded (conflict-free)
  const int bid = blockIdx.x;
  const int t = threadIdx.x;

  if (bid < PA_BLOCKS) {
    // ---- prep_a: one sx row -> fp16
    const int r = bid;
    const float4 v = *(const float4*)&sx[(size_t)r * FEAT_DIM + t * 4];
    f16x4 h = {(_Float16)v.x, (_Float16)v.y, (_Float16)v.z, (_Float16)v.w};
    *(f16x4*)&A1[(size_t)r * FEAT_DIM + t * 4] = h;
  } else if (bid < PA_BLOCKS + PW_BLOCKS) {
    // ---- prep_w: W (k-major) -> W1 (n-major fp16) via LDS transpose.
    const int k0 = (bid - PA_BLOCKS) * 64;
#pragma unroll 8
    for (int kk = 0; kk < 64; kk++) {
      Lw[t][kk] = (_Float16)W[(size_t)(k0 + kk) * PROJ_DIM + t];
    }
    __syncthreads();
#pragma unroll
    for (int i = 0; i < 8; i++) {
      *(f16x8*)&W1[(size_t)t * FEAT_DIM + k0 + i * 8] =
          *(f16x8*)&Lw[t][i * 8];
    }
  } else {
    // ---- proj_x: xq = x @ W (fp32), 32 cols x 8 k-slices per block
    const int pxb = bid - PA_BLOCKS - PW_BLOCKS;
    const int b = pxb >> 3, cc = pxb & 7;
    if (pxb == 0 && t < BATCH) rowmaxU[t] = 0u;  // encoded -inf

    const int col = t & 31, ks = t >> 5;
    const int gc = cc * 32 + col;
    const int k0 = ks * 128;
    float s = 0.f;
#pragma unroll 8
    for (int k = 0; k < 128; k++) {
      s = fmaf(x[(size_t)b * FEAT_DIM + k0 + k],
               W[(size_t)(k0 + k) * PROJ_DIM + gc], s);
    }
    part[t] = s;
    __syncthreads();
    if (t < 32) {
      float acc = 0.f;
#pragma unroll
      for (int i = 0; i < 8; i++) acc += part[i * 32 + t];
      xq[(size_t)b * PROJ_DIM + cc * 32 + t] = acc;
    }
  }
}

// ---------------------------------------------------------------------------
// sxp16 = fp16(A1 @ W1^T), K=1024, single-term fp16 (no split, no atomics —
// round-5 lesson: cross-XCD atomic combine serializes; round-6 lesson: total
// L3 bytes are the currency, so shrink the operand, not the schedule).
// Tile 128x64, BK=64, 4 waves (2x2), wave tile 64x32 (4x2 frags of 16x16x32).
// Flat grid 256, XCD-swizzled: bm = bid&63 so the 4 column-tiles of one
// row-block share bid%8 -> same XCD -> A row-block (256 KB fp16) stays in L2.
// ---------------------------------------------------------------------------
__global__ __launch_bounds__(256) void sxp_mfma_kernel(
    const _Float16* __restrict__ A1, const _Float16* __restrict__ W1,
    _Float16* __restrict__ sxp16) {
  __shared__ _Float16 At[128 * 64];  // row r: 8 chunks of 8 halfs
  __shared__ _Float16 Bt[64 * 64];

  const int tid = threadIdx.x;
  const int w = tid >> 6;
  const int lane = tid & 63;
  const int bm = (blockIdx.x & 63) * 128;  // XCD swizzle: bid%8 == bm-group%8
  const int bn = (blockIdx.x >> 6) * 64;
  const int wm = w & 1, wn = w >> 1;
  const int m16 = lane & 15, quad = lane >> 4;
  const int lrow8 = lane >> 3;       // 0..7
  const int g = (lane & 7) ^ lrow8;  // XOR-swizzled global chunk index

  f32x4 acc[4][2];
#pragma unroll
  for (int mt = 0; mt < 4; mt++)
#pragma unroll
    for (int nt = 0; nt < 2; nt++) acc[mt][nt] = (f32x4){0.f, 0.f, 0.f, 0.f};

  for (int kb = 0; kb < FEAT_DIM; kb += 64) {
    // stage A tile (128 x 64 fp16): 4 instrs/wave, 8 rows each
#pragma unroll
    for (int i = 0; i < 4; i++) {
      const int row = w * 32 + i * 8 + lrow8;
      const _Float16* gp = A1 + (size_t)(bm + row) * FEAT_DIM + kb + g * 8;
      __builtin_amdgcn_global_load_lds(
          (const __attribute__((address_space(1))) void*)gp,
          (__attribute__((address_space(3))) void*)(At + (w * 32 + i * 8) * 64),
          16, 0, 0);
    }
    // stage B tile (64 n x 64 k fp16): 2 instrs/wave
#pragma unroll
    for (int i = 0; i < 2; i++) {
      const int nrow = w * 16 + i * 8 + lrow8;
      const _Float16* gp = W1 + (size_t)(bn + nrow) * FEAT_DIM + kb + g * 8;
      __builtin_amdgcn_global_load_lds(
          (const __attribute__((address_space(1))) void*)gp,
          (__attribute__((address_space(3))) void*)(Bt + (w * 16 + i * 8) * 64),
          16, 0, 0);
    }
    __syncthreads();

#pragma unroll
    for (int s = 0; s < 2; s++) {
      const int slot = (s * 4 + quad) ^ (m16 & 7);
      f16x8 af[4], bf[2];
#pragma unroll
      for (int mt = 0; mt < 4; mt++) {
        const int row = wm * 64 + mt * 16 + m16;
        af[mt] = *(f16x8*)&At[row * 64 + slot * 8];
      }
#pragma unroll
      for (int nt = 0; nt < 2; nt++) {
        const int nrow = wn * 32 + nt * 16 + m16;
        bf[nt] = *(f16x8*)&Bt[nrow * 64 + slot * 8];
      }
#pragma unroll
      for (int mt = 0; mt < 4; mt++)
#pragma unroll
        for (int nt = 0; nt < 2; nt++)
          acc[mt][nt] = __builtin_amdgcn_mfma_f32_16x16x32_f16(
              af[mt], bf[nt], acc[mt][nt], 0, 0, 0);
    }
    __syncthreads();
  }

  // store fp16 sxp. C/D layout: col = lane&15 (n), row = quad*4 + reg (m)
#pragma unroll
  for (int mt = 0; mt < 4; mt++)
#pragma unroll
    for (int nt = 0; nt < 2; nt++)
#pragma unroll
      for (int r = 0; r < 4; r++) {
        const int mg = bm + wm * 64 + mt * 16 + quad * 4 + r;
        const int ng = bn + wn * 32 + nt * 16 + m16;
        sxp16[(size_t)mg * PROJ_DIM + ng] = (_Float16)acc[mt][nt][r];
      }
}

// ---------------------------------------------------------------------------
// score: scores[b][j] = 2<xq_b, sxp_j> - ||sxp_j||^2 - ||xq_b||^2.
// fp16 sxp streamed from global (16 B/lane coalesced); xq as packed fp16 in
// LDS (wave-uniform broadcast reads); fdot2 with fp32 accumulate.
// Grid (32 j-chunks, 8 b-groups of 4).
// ---------------------------------------------------------------------------
__global__ __launch_bounds__(256) void score_kernel(
    const float* __restrict__ xq, const _Float16* __restrict__ sxp16,
    float* __restrict__ sc, unsigned* __restrict__ rowmaxU) {
  __shared__ _Float16 xqh[4 * PROJ_DIM];  // [b][p], b-major
  __shared__ float xsqL[4];
  __shared__ float redm[4][4];

  const int t = threadIdx.x;
  const int jc = blockIdx.x;
  const int bg = blockIdx.y;
  const int lane = t & 63, wave = t >> 6;

  float xv[4];
#pragma unroll
  for (int i = 0; i < 4; i++) {
    xv[i] = xq[(size_t)(bg * 4 + i) * PROJ_DIM + t];
    xqh[i * PROJ_DIM + t] = (_Float16)xv[i];
  }
#pragma unroll
  for (int i = 0; i < 4; i++) {
    float v = xv[i] * xv[i];
#pragma unroll
    for (int o = 1; o < 64; o <<= 1) v += __shfl_xor(v, o, 64);
    if (lane == 0) redm[i][wave] = v;
  }
  __syncthreads();
  if (t < 4) xsqL[t] = redm[t][0] + redm[t][1] + redm[t][2] + redm[t][3];
  __syncthreads();

  const int j = jc * 256 + t;
  const f16x8* __restrict__ rowp =
      (const f16x8*)(sxp16 + (size_t)j * PROJ_DIM);
  float dot[4] = {0.f, 0.f, 0.f, 0.f};
  float rsq = 0.f;

#pragma unroll 4
  for (int q = 0; q < PROJ_DIM / 8; q++) {
    const f16x8 hv = rowp[q];
    const f16x2* hp = (const f16x2*)&hv;
#pragma unroll
    for (int b = 0; b < 4; b++) {
      const f16x8 xb = *(const f16x8*)&xqh[b * PROJ_DIM + q * 8];
      const f16x2* xp = (const f16x2*)&xb;
#pragma unroll
      for (int i = 0; i < 4; i++)
        dot[b] = __builtin_amdgcn_fdot2(hp[i], xp[i], dot[b], false);
    }
#pragma unroll
    for (int i = 0; i < 4; i++)
      rsq = __builtin_amdgcn_fdot2(hp[i], hp[i], rsq, false);
  }

#pragma unroll
  for (int c = 0; c < 4; c++) {
    const float s = 2.0f * dot[c] - rsq - xsqL[c];
    sc[(size_t)(bg * 4 + c) * NUM_SUPPORT + j] = s;
    float v = s;
#pragma unroll
    for (int o = 1; o < 64; o <<= 1) v = fmaxf(v, __shfl_xor(v, o, 64));
    if (lane == 0) redm[c][wave] = v;
  }
  __syncthreads();
  if (t < 4) {
    const float m =
        fmaxf(fmaxf(redm[t][0], redm[t][1]), fmaxf(redm[t][2], redm[t][3]));
    atomicMax(&rowmaxU[bg * 4 + t], enc_f(m));
  }
}

// ---------------------------------------------------------------------------
// finish: exp, class bins, log. One block (1024 thr) per batch row.
// ---------------------------------------------------------------------------
__global__ __launch_bounds__(1024) void finish_kernel(
    const float* __restrict__ sc, const unsigned* __restrict__ rowmaxU,
    const int* __restrict__ sy, float* __restrict__ out) {
  __shared__ float cls[N_CLASSES];
  __shared__ float red[16];

  const int b = blockIdx.x;
  const int t = threadIdx.x;
  const int lane = t & 63, wave = t >> 6;
  const float m = dec_f(rowmaxU[b]);

  for (int c = t; c < N_CLASSES; c += 1024) cls[c] = 0.0f;
  __syncthreads();

  float lsum = 0.0f;
#pragma unroll
  for (int jj = 0; jj < NUM_SUPPORT / 1024; jj++) {
    const int j = jj * 1024 + t;
    const float e = expf(sc[(size_t)b * NUM_SUPPORT + j] - m);
    lsum += e;
    atomicAdd(&cls[sy[j]], e);
  }
#pragma unroll
  for (int o = 1; o < 64; o <<= 1) lsum += __shfl_xor(lsum, o, 64);
  if (lane == 0) red[wave] = lsum;
  __syncthreads();
  if (t == 0) {
    float s = 0.f;
#pragma unroll
    for (int i = 0; i < 16; i++) s += red[i];
    red[0] = s;
  }
  __syncthreads();
  const float inv = 1.0f / red[0];
  for (int c = t; c < N_CLASSES; c += 1024) {
    out[(size_t)b * N_CLASSES + c] = logf(cls[c] * inv + 1e-12f);
  }
}

// ---------------------------------------------------------------------------
extern "C" void kernel_launch(void* const* d_in, const int* in_sizes, int n_in,
                              void* d_out, int out_size, void* d_ws,
                              size_t ws_size, hipStream_t stream) {
  const float* x = (const float*)d_in[0];   // (32, 1024)
  const float* sx = (const float*)d_in[1];  // (8192, 1024)
  const float* W = (const float*)d_in[2];   // (1024, 256)
  const int* sy = (const int*)d_in[3];      // (8192,)
  float* out = (float*)d_out;               // (32, 1000)

  char* p = (char*)d_ws;
  float* xq = (float*)p;            p += (size_t)BATCH * PROJ_DIM * 4;
  unsigned* rowmaxU = (unsigned*)p; p += 128;
  _Float16* sxp16 = (_Float16*)p;   p += (size_t)NUM_SUPPORT * PROJ_DIM * 2;
  float* sc = (float*)p;            p += (size_t)BATCH * NUM_SUPPORT * 4;
  _Float16* A1 = (_Float16*)p;      p += (size_t)NUM_SUPPORT * FEAT_DIM * 2;
  _Float16* W1 = (_Float16*)p;      // 256*1024*2

  prelude_kernel<<<dim3(PA_BLOCKS + PW_BLOCKS + PX_BLOCKS), dim3(256), 0,
                   stream>>>(sx, W, x, A1, W1, xq, rowmaxU);
  sxp_mfma_kernel<<<dim3(256), dim3(256), 0, stream>>>(A1, W1, sxp16);
  score_kernel<<<dim3(NUM_SUPPORT / 256, BATCH / 4), dim3(256), 0, stream>>>(
      xq, sxp16, sc, rowmaxU);
  finish_kernel<<<dim3(BATCH), dim3(1024), 0, stream>>>(sc, rowmaxU, sy, out);
}

// Round 8
// 120.263 us; speedup vs baseline: 1.5171x; 1.0884x over previous
//
#include <hip/hip_runtime.h>
#include <math.h>

#define N_CLASSES 1000
#define FEAT_DIM 1024
#define PROJ_DIM 256
#define BATCH 32
#define NUM_SUPPORT 8192

// prelude grid layout
#define PA_BLOCKS 8192  // prep_a: one sx row each
#define PW_BLOCKS 16    // prep_w: 64-k tile each
#define PX_BLOCKS 256   // proj_x (32 b x 8 cc)
#define PZ_BLOCKS 256   // zero sc (1 MB)

typedef __attribute__((ext_vector_type(8))) _Float16 f16x8;
typedef __attribute__((ext_vector_type(4))) _Float16 f16x4;
typedef __attribute__((ext_vector_type(2))) _Float16 f16x2;
typedef __attribute__((ext_vector_type(4))) float f32x4;

// ---------------------------------------------------------------------------
// Prelude (one dispatch): prep_a (sx->fp16) | prep_w (W->fp16 n-major) |
// proj_x (xqh2 = fp16(2*x@W)) | zero sc. Branch is uniform per block.
// Note: the per-b constant -||xq_b||^2 cancels in softmax, so no xsq/fp32 xq.
// ---------------------------------------------------------------------------
__global__ __launch_bounds__(256) void prelude_kernel(
    const float* __restrict__ sx, const float* __restrict__ W,
    const float* __restrict__ x, _Float16* __restrict__ A1,
    _Float16* __restrict__ W1, _Float16* __restrict__ xqh2,
    float* __restrict__ sc) {
  __shared__ float part[256];
  __shared__ _Float16 Lw[256][66];  // transpose tile, padded
  const int bid = blockIdx.x;
  const int t = threadIdx.x;

  if (bid < PA_BLOCKS) {
    // ---- prep_a: one sx row -> fp16
    const int r = bid;
    const float4 v = *(const float4*)&sx[(size_t)r * FEAT_DIM + t * 4];
    f16x4 h = {(_Float16)v.x, (_Float16)v.y, (_Float16)v.z, (_Float16)v.w};
    *(f16x4*)&A1[(size_t)r * FEAT_DIM + t * 4] = h;
  } else if (bid < PA_BLOCKS + PW_BLOCKS) {
    // ---- prep_w: W (k-major) -> W1 (n-major fp16) via LDS transpose.
    const int k0 = (bid - PA_BLOCKS) * 64;
#pragma unroll 8
    for (int kk = 0; kk < 64; kk++) {
      Lw[t][kk] = (_Float16)W[(size_t)(k0 + kk) * PROJ_DIM + t];
    }
    __syncthreads();
#pragma unroll
    for (int i = 0; i < 8; i++) {
      *(f16x8*)&W1[(size_t)t * FEAT_DIM + k0 + i * 8] = *(f16x8*)&Lw[t][i * 8];
    }
  } else if (bid < PA_BLOCKS + PW_BLOCKS + PX_BLOCKS) {
    // ---- proj_x: xqh2[b][col] = fp16(2 * (x@W)[b][col])
    const int pxb = bid - PA_BLOCKS - PW_BLOCKS;
    const int b = pxb >> 3, cc = pxb & 7;
    const int col = t & 31, ks = t >> 5;
    const int gc = cc * 32 + col;
    const int k0 = ks * 128;
    float s = 0.f;
#pragma unroll 8
    for (int k = 0; k < 128; k++) {
      s = fmaf(x[(size_t)b * FEAT_DIM + k0 + k],
               W[(size_t)(k0 + k) * PROJ_DIM + gc], s);
    }
    part[t] = s;
    __syncthreads();
    if (t < 32) {
      float acc = 0.f;
#pragma unroll
      for (int i = 0; i < 8; i++) acc += part[i * 32 + t];
      xqh2[(size_t)b * PROJ_DIM + cc * 32 + t] = (_Float16)(2.0f * acc);
    }
  } else {
    // ---- zero sc (atomicAdd target; ws is re-poisoned every launch)
    const int zb = bid - PA_BLOCKS - PW_BLOCKS - PX_BLOCKS;
    float4 z = {0.f, 0.f, 0.f, 0.f};
    *(float4*)&sc[(size_t)zb * 1024 + t * 4] = z;
  }
}

// ---------------------------------------------------------------------------
// gemm_score: 64x64 tile of sxp = A1 @ W1^T (fp16 MFMA, K=1024) computed in
// registers, then fused score epilogue: for its 64 j's and all 32 b's,
//   sc[b][j] += sum_n( sxp[j][n] * 2*xq[b][n] ) - sum_n( sxp[j][n]^2 )
// via one atomicAdd per (b,j) (4-way contention: 4 n-tiles, XCD-local by
// swizzle). sxp is never materialized to global.
// Grid 512 flat: xcd = bid&7, idx = bid>>3, m = xcd*16 + (idx&15), n = idx>>4
// -> all 4 n-tiles of one m-tile on one XCD (A row-block L2-resident; the 4
// sc RMWs per address stay on one XCD — round-5 lesson).
// ---------------------------------------------------------------------------
__global__ __launch_bounds__(256) void gemm_score_kernel(
    const _Float16* __restrict__ A1, const _Float16* __restrict__ W1,
    const _Float16* __restrict__ xqh2, float* __restrict__ sc) {
  __shared__ _Float16 At[64 * 64];  // staging, XOR-swizzled chunks
  __shared__ _Float16 Bt[64 * 64];
  __shared__ _Float16 Sx[64 * 72];  // sxp tile, padded stride 72
  __shared__ _Float16 Xl[32 * 64];  // 2*xq slice for this n-chunk

  const int tid = threadIdx.x;
  const int w = tid >> 6;
  const int lane = tid & 63;
  const int xcd = blockIdx.x & 7;
  const int idx = blockIdx.x >> 3;
  const int bm = (xcd * 16 + (idx & 15)) * 64;  // 0..127 m-tiles
  const int bn = (idx >> 4) * 64;               // 0..3 n-tiles
  const int wm = w & 1, wn = w >> 1;
  const int m16 = lane & 15, quad = lane >> 4;
  const int lrow8 = lane >> 3;       // 0..7
  const int g = (lane & 7) ^ lrow8;  // XOR-swizzled global chunk index

  // load Xl: 32 b-rows x 64 halfs (this block's n-range)
  {
    const int r = tid >> 3, c = tid & 7;
    *(f16x8*)&Xl[r * 64 + c * 8] =
        *(const f16x8*)&xqh2[(size_t)r * PROJ_DIM + bn + c * 8];
  }

  f32x4 acc[2][2];
#pragma unroll
  for (int mt = 0; mt < 2; mt++)
#pragma unroll
    for (int nt = 0; nt < 2; nt++) acc[mt][nt] = (f32x4){0.f, 0.f, 0.f, 0.f};

  for (int kb = 0; kb < FEAT_DIM; kb += 64) {
    // stage A tile (64 x 64 fp16): 2 instrs/wave, 8 rows each
#pragma unroll
    for (int i = 0; i < 2; i++) {
      const int row = w * 16 + i * 8 + lrow8;
      const _Float16* gp = A1 + (size_t)(bm + row) * FEAT_DIM + kb + g * 8;
      __builtin_amdgcn_global_load_lds(
          (const __attribute__((address_space(1))) void*)gp,
          (__attribute__((address_space(3))) void*)(At + (w * 16 + i * 8) * 64),
          16, 0, 0);
    }
    // stage B tile (64 n x 64 k fp16): 2 instrs/wave
#pragma unroll
    for (int i = 0; i < 2; i++) {
      const int nrow = w * 16 + i * 8 + lrow8;
      const _Float16* gp = W1 + (size_t)(bn + nrow) * FEAT_DIM + kb + g * 8;
      __builtin_amdgcn_global_load_lds(
          (const __attribute__((address_space(1))) void*)gp,
          (__attribute__((address_space(3))) void*)(Bt + (w * 16 + i * 8) * 64),
          16, 0, 0);
    }
    __syncthreads();

#pragma unroll
    for (int s = 0; s < 2; s++) {
      const int slot = (s * 4 + quad) ^ (m16 & 7);
      f16x8 af[2], bf[2];
#pragma unroll
      for (int mt = 0; mt < 2; mt++) {
        const int row = wm * 32 + mt * 16 + m16;
        af[mt] = *(f16x8*)&At[row * 64 + slot * 8];
      }
#pragma unroll
      for (int nt = 0; nt < 2; nt++) {
        const int nrow = wn * 32 + nt * 16 + m16;
        bf[nt] = *(f16x8*)&Bt[nrow * 64 + slot * 8];
      }
#pragma unroll
      for (int mt = 0; mt < 2; mt++)
#pragma unroll
        for (int nt = 0; nt < 2; nt++)
          acc[mt][nt] = __builtin_amdgcn_mfma_f32_16x16x32_f16(
              af[mt], bf[nt], acc[mt][nt], 0, 0, 0);
    }
    __syncthreads();
  }

  // ---- epilogue: write sxp tile to LDS (fp16, padded stride 72).
  // C/D layout: col = lane&15 (n), row = quad*4 + reg (m/j)
#pragma unroll
  for (int mt = 0; mt < 2; mt++)
#pragma unroll
    for (int nt = 0; nt < 2; nt++)
#pragma unroll
      for (int r = 0; r < 4; r++) {
        const int jl = wm * 32 + mt * 16 + quad * 4 + r;
        const int nl = wn * 32 + nt * 16 + m16;
        Sx[jl * 72 + nl] = (_Float16)acc[mt][nt][r];
      }
  __syncthreads();

  // ---- fused partial score: thread t -> j = t&63, b-group = t>>6 (8 b's).
  // Whole wave shares b-group -> Xl reads are same-address broadcasts.
  const int j = tid & 63;
  const int bg = tid >> 6;
  float dotb[8] = {0.f, 0.f, 0.f, 0.f, 0.f, 0.f, 0.f, 0.f};
  float rsq = 0.f;
#pragma unroll
  for (int c = 0; c < 8; c++) {
    const f16x8 hv = *(const f16x8*)&Sx[j * 72 + c * 8];
    const f16x2* hp = (const f16x2*)&hv;
#pragma unroll
    for (int i = 0; i < 4; i++)
      rsq = __builtin_amdgcn_fdot2(hp[i], hp[i], rsq, false);
#pragma unroll
    for (int b8 = 0; b8 < 8; b8++) {
      const f16x8 xv = *(const f16x8*)&Xl[(bg * 8 + b8) * 64 + c * 8];
      const f16x2* xp = (const f16x2*)&xv;
#pragma unroll
      for (int i = 0; i < 4; i++)
        dotb[b8] = __builtin_amdgcn_fdot2(hp[i], xp[i], dotb[b8], false);
    }
  }
#pragma unroll
  for (int b8 = 0; b8 < 8; b8++) {
    atomicAdd(&sc[(size_t)(bg * 8 + b8) * NUM_SUPPORT + bm + j],
              dotb[b8] - rsq);
  }
}

// ---------------------------------------------------------------------------
// finish: per batch row: row max (in-kernel), exp, class bins, log.
// One block (1024 thr) per b; row values kept in registers between passes.
// ---------------------------------------------------------------------------
__global__ __launch_bounds__(1024) void finish_kernel(
    const float* __restrict__ sc, const int* __restrict__ sy,
    float* __restrict__ out) {
  __shared__ float cls[N_CLASSES];
  __shared__ float redm[16];
  __shared__ float reds[16];

  const int b = blockIdx.x;
  const int t = threadIdx.x;
  const int lane = t & 63, wave = t >> 6;

  float v[8];
  float m = -1e30f;
#pragma unroll
  for (int jj = 0; jj < 8; jj++) {
    v[jj] = sc[(size_t)b * NUM_SUPPORT + jj * 1024 + t];
    m = fmaxf(m, v[jj]);
  }
#pragma unroll
  for (int o = 1; o < 64; o <<= 1) m = fmaxf(m, __shfl_xor(m, o, 64));
  if (lane == 0) redm[wave] = m;
  if (t < N_CLASSES) cls[t] = 0.0f;
  __syncthreads();
  float gm = redm[0];
#pragma unroll
  for (int i = 1; i < 16; i++) gm = fmaxf(gm, redm[i]);

  float lsum = 0.0f;
#pragma unroll
  for (int jj = 0; jj < 8; jj++) {
    const float e = expf(v[jj] - gm);
    lsum += e;
    atomicAdd(&cls[sy[jj * 1024 + t]], e);
  }
#pragma unroll
  for (int o = 1; o < 64; o <<= 1) lsum += __shfl_xor(lsum, o, 64);
  if (lane == 0) reds[wave] = lsum;
  __syncthreads();
  float total = 0.f;
#pragma unroll
  for (int i = 0; i < 16; i++) total += reds[i];
  const float inv = 1.0f / total;
  if (t < N_CLASSES) {
    out[(size_t)b * N_CLASSES + t] = logf(cls[t] * inv + 1e-12f);
  }
}

// ---------------------------------------------------------------------------
extern "C" void kernel_launch(void* const* d_in, const int* in_sizes, int n_in,
                              void* d_out, int out_size, void* d_ws,
                              size_t ws_size, hipStream_t stream) {
  const float* x = (const float*)d_in[0];   // (32, 1024)
  const float* sx = (const float*)d_in[1];  // (8192, 1024)
  const float* W = (const float*)d_in[2];   // (1024, 256)
  const int* sy = (const int*)d_in[3];      // (8192,)
  float* out = (float*)d_out;               // (32, 1000)

  char* p = (char*)d_ws;
  float* sc = (float*)p;          p += (size_t)BATCH * NUM_SUPPORT * 4;
  _Float16* A1 = (_Float16*)p;    p += (size_t)NUM_SUPPORT * FEAT_DIM * 2;
  _Float16* W1 = (_Float16*)p;    p += (size_t)PROJ_DIM * FEAT_DIM * 2;
  _Float16* xqh2 = (_Float16*)p;  // 32*256*2

  prelude_kernel<<<dim3(PA_BLOCKS + PW_BLOCKS + PX_BLOCKS + PZ_BLOCKS),
                   dim3(256), 0, stream>>>(sx, W, x, A1, W1, xqh2, sc);
  gemm_score_kernel<<<dim3(512), dim3(256), 0, stream>>>(A1, W1, xqh2, sc);
  finish_kernel<<<dim3(BATCH), dim3(1024), 0, stream>>>(sc, sy, out);
}